// Round 2
// baseline (21744.897 us; speedup 1.0000x reference)
//
#include <hip/hip_runtime.h>

// VanillaRNN B=64,S=2048,I=128,H=512,O=128. ALL inputs fp32; OUTPUT fp32
// (outputs [64][2048][128] then h_final [64][512], flat-concatenated fp32).
//
// Single fused kernel: 128 blocks x 512 threads; block PAIR (i, i+64) owns
// batch b = i&63 (w = i>>6 selects the H-half). With round-robin block->XCD
// dispatch (block i -> XCD i%8), both members of a pair land on the SAME
// XCD, so the per-step h-exchange can be served by the shared per-XCD L2
// (~250 cyc round trip) instead of the cross-XCD coherence point (~900+).
// Exchange protocol (correctness does NOT depend on the XCD mapping):
//   publish: sc0 (L1-bypass, L2-coherent) store to FAST slot + agent-scope
//            atomic store to SLOW slot (both tagged u64: tag=t+1 in hi32).
//   poll:    bounded sc0 spin on FAST slot; on timeout, unbounded
//            agent-scope spin on SLOW slot (round-0's proven protocol).
// Tags 1..2048 never match ws poison 0xAA.. ; same-parity slot reuse
// (t vs t+2) is barrier-ordered safe as in round-0 (a WG publishes t+3
// only after its partner has consumed t+1).
// Each WG holds its 256x512 W_rec slice + W_in slice + 64x512 W_out slice
// in VGPRs as fp16 (v_dot2_f32_f16, fp32 accumulate). Per step:
//   - GEMV h-preacts from LDS h (bank-conflict-free chunked layout), fused
//     input projection (x prefetched one step ahead), plus output row t-1.
//   - 8-lane butterfly reduce, tanh on c==0 lanes, publish 256 h values,
//     pull partner's 256.
// 128 WGs <= 256 CUs -> all co-resident, exchange cannot deadlock.
// __launch_bounds__(512,1): only 1 WG/CU is resident anyway; the 256-VGPR
// budget keeps the persistent weights in arch VGPRs.
// ws: fast[64][2][2][128] u64 (256 KiB) + slow[64][2][2][128] u64 (256 KiB).

typedef _Float16 half2_t __attribute__((ext_vector_type(2)));
typedef _Float16 half8_t __attribute__((ext_vector_type(8)));
typedef float    float2_t __attribute__((ext_vector_type(2)));
typedef float    float4_t __attribute__((ext_vector_type(4)));

#define BB 64
#define SS 2048
#define IN 128
#define HH 512
#define OO 128
#define FAST_SPINS 100

using u32 = unsigned int;
using u64 = unsigned long long;

__device__ __forceinline__ float fdot2f(half2_t a, half2_t b, float c) {
#if __has_builtin(__builtin_amdgcn_fdot2)
    return __builtin_amdgcn_fdot2(a, b, c, false);
#else
    return c + (float)a[0] * (float)b[0] + (float)a[1] * (float)b[1];
#endif
}
__device__ __forceinline__ half2_t h2(float a, float b) {
    return half2_t{(_Float16)a, (_Float16)b};
}

// L1-bypassing, L2-served load (coherent within an XCD). Early-clobber dest:
// must not alias the address pair (re-used across spin iterations).
__device__ __forceinline__ u64 ld_sc0(const u64* p) {
    u64 v;
    asm volatile("global_load_dwordx2 %0, %1, off sc0\n\t"
                 "s_waitcnt vmcnt(0)"
                 : "=&v"(v) : "v"(p) : "memory");
    return v;
}
// Write-through-to-L2 store (vL1 is write-through; sc0 for certainty).
__device__ __forceinline__ void st_sc0(u64* p, u64 v) {
    asm volatile("global_store_dwordx2 %0, %1, off sc0"
                 :: "v"(p), "v"(v) : "memory");
}

__global__ __launch_bounds__(512, 1) void rnn_fused(
    const float* __restrict__ inputs,   // [B][S][I]
    const float* __restrict__ h0,       // [B][H]
    const float* __restrict__ W_in,     // [H][I]
    const float* __restrict__ W_in_b,   // [H]
    const float* __restrict__ W_rec,    // [H][H]
    const float* __restrict__ W_out,    // [O][H]
    const float* __restrict__ W_out_b,  // [O]
    float* __restrict__ outp,           // fp32 [B][S][O]
    float* __restrict__ hfinal,         // fp32 [B][H]
    u64* __restrict__ hexf,             // fast slots [B][2][2][128]
    u64* __restrict__ hexs,             // slow slots [B][2][2][128]
    int use_fast)
{
    const int tid = threadIdx.x;
    const int bb = blockIdx.x & 63;    // batch: pair (i, i+64) -> same XCD
    const int w  = blockIdx.x >> 6;    // which half of H this WG produces
    const int c  = tid & 7;            // k-chunk (64 h values each)
    const int q  = tid >> 3;           // j-quad / o index
    const int og = w * 64 + q;         // this thread-group's output column

    // h as half2, chunk-strided 36 dwords: lane c's b128 reads start at
    // bank (9c+kb*4)%32 -> distinct across the 8 c-lanes, conflict-free.
    __shared__ __align__(16) half2_t hbuf[288];
    // input row as half2, chunk stride 12 dwords, double-buffered.
    __shared__ __align__(16) half2_t xh[2][96];

    // ---- persistent weights in VGPRs (fp32 -> fp16 once)
    half2_t wr[4][32];   // W_rec[jg][c*64 + 2m..]
    half2_t wi[4][8];    // W_in [jg][c*16 + 2m..]
    half2_t wo[32];      // W_out[og][c*64 + 2m..]
    float bias[4];

    #pragma unroll
    for (int jj = 0; jj < 4; ++jj) {
        const int jg = w * 256 + q * 4 + jj;
        const float4_t* rrow = (const float4_t*)(W_rec + jg * HH + c * 64);
        #pragma unroll
        for (int m = 0; m < 16; ++m) {
            const float4_t u = rrow[m];
            wr[jj][m * 2 + 0] = h2(u[0], u[1]);
            wr[jj][m * 2 + 1] = h2(u[2], u[3]);
        }
        const float4_t* irow = (const float4_t*)(W_in + jg * IN + c * 16);
        #pragma unroll
        for (int m = 0; m < 4; ++m) {
            const float4_t u = irow[m];
            wi[jj][m * 2 + 0] = h2(u[0], u[1]);
            wi[jj][m * 2 + 1] = h2(u[2], u[3]);
        }
        bias[jj] = W_in_b[jg];
    }
    {
        const float4_t* orow = (const float4_t*)(W_out + og * HH + c * 64);
        #pragma unroll
        for (int m = 0; m < 16; ++m) {
            const float4_t u = orow[m];
            wo[m * 2 + 0] = h2(u[0], u[1]);
            wo[m * 2 + 1] = h2(u[2], u[3]);
        }
    }
    const float bo = W_out_b[og];

    // ---- init LDS: h = h0 (fp32->fp16), x row 0
    if (tid < 256) {
        const float2_t u = *(const float2_t*)(h0 + bb * HH + tid * 2);
        const int k = tid * 2;
        hbuf[(k >> 6) * 36 + ((k & 63) >> 1)] = h2(u[0], u[1]);
    }
    if (tid >= 256 && tid < 320) {
        const int i2 = tid - 256;
        const float2_t u = *(const float2_t*)(inputs +
                              (size_t)(bb * SS + 0) * IN + i2 * 2);
        xh[0][(i2 >> 3) * 12 + (i2 & 7)] = h2(u[0], u[1]);
    }
    __syncthreads();

    for (int t = 0; t < SS; ++t) {
        // ---- recurrence partials + output-row(t-1) partials, lane's k-chunk
        float acc[4] = {0.f, 0.f, 0.f, 0.f};
        float oa = 0.f;
        const half2_t* hb = &hbuf[c * 36];
        #pragma unroll
        for (int kb = 0; kb < 8; ++kb) {
            const half8_t hv = *(const half8_t*)(hb + kb * 4);
            const half2_t p0 = __builtin_shufflevector(hv, hv, 0, 1);
            const half2_t p1 = __builtin_shufflevector(hv, hv, 2, 3);
            const half2_t p2 = __builtin_shufflevector(hv, hv, 4, 5);
            const half2_t p3 = __builtin_shufflevector(hv, hv, 6, 7);
            #pragma unroll
            for (int jj = 0; jj < 4; ++jj) {
                acc[jj] = fdot2f(wr[jj][kb * 4 + 0], p0, acc[jj]);
                acc[jj] = fdot2f(wr[jj][kb * 4 + 1], p1, acc[jj]);
                acc[jj] = fdot2f(wr[jj][kb * 4 + 2], p2, acc[jj]);
                acc[jj] = fdot2f(wr[jj][kb * 4 + 3], p3, acc[jj]);
            }
            oa = fdot2f(wo[kb * 4 + 0], p0, oa);
            oa = fdot2f(wo[kb * 4 + 1], p1, oa);
            oa = fdot2f(wo[kb * 4 + 2], p2, oa);
            oa = fdot2f(wo[kb * 4 + 3], p3, oa);
        }
        // ---- fused input projection (lane's 16 of 128 inputs)
        {
            const half2_t* xb = &xh[t & 1][c * 12];
            const half8_t xv0 = *(const half8_t*)(xb);
            const half8_t xv1 = *(const half8_t*)(xb + 4);
            const half2_t x0 = __builtin_shufflevector(xv0, xv0, 0, 1);
            const half2_t x1 = __builtin_shufflevector(xv0, xv0, 2, 3);
            const half2_t x2 = __builtin_shufflevector(xv0, xv0, 4, 5);
            const half2_t x3 = __builtin_shufflevector(xv0, xv0, 6, 7);
            const half2_t x4 = __builtin_shufflevector(xv1, xv1, 0, 1);
            const half2_t x5 = __builtin_shufflevector(xv1, xv1, 2, 3);
            const half2_t x6 = __builtin_shufflevector(xv1, xv1, 4, 5);
            const half2_t x7 = __builtin_shufflevector(xv1, xv1, 6, 7);
            #pragma unroll
            for (int jj = 0; jj < 4; ++jj) {
                acc[jj] = fdot2f(wi[jj][0], x0, acc[jj]);
                acc[jj] = fdot2f(wi[jj][1], x1, acc[jj]);
                acc[jj] = fdot2f(wi[jj][2], x2, acc[jj]);
                acc[jj] = fdot2f(wi[jj][3], x3, acc[jj]);
                acc[jj] = fdot2f(wi[jj][4], x4, acc[jj]);
                acc[jj] = fdot2f(wi[jj][5], x5, acc[jj]);
                acc[jj] = fdot2f(wi[jj][6], x6, acc[jj]);
                acc[jj] = fdot2f(wi[jj][7], x7, acc[jj]);
            }
        }
        // ---- butterfly reduce over the 8 c-lanes
        #pragma unroll
        for (int jj = 0; jj < 4; ++jj) {
            float v = acc[jj];
            v += __shfl_xor(v, 1);
            v += __shfl_xor(v, 2);
            v += __shfl_xor(v, 4);
            acc[jj] = v;
        }
        oa += __shfl_xor(oa, 1);
        oa += __shfl_xor(oa, 2);
        oa += __shfl_xor(oa, 4);

        __syncthreads();   // all hbuf/xh reads of step t complete

        if (c == 0) {
            if (t > 0)
                outp[(size_t)(bb * SS + (t - 1)) * OO + og] = oa + bo;
            const float v0 = tanhf(acc[0] + bias[0]);
            const float v1 = tanhf(acc[1] + bias[1]);
            const float v2 = tanhf(acc[2] + bias[2]);
            const float v3 = tanhf(acc[3] + bias[3]);
            const half2_t ha = h2(v0, v1);
            const half2_t hc = h2(v2, v3);
            const u32 la = __builtin_bit_cast(u32, ha);
            const u32 lb = __builtin_bit_cast(u32, hc);
            const int kg = w * 256 + q * 4;
            const int pos = (kg >> 6) * 36 + ((kg & 63) >> 1);
            hbuf[pos]     = ha;
            hbuf[pos + 1] = hc;
            const u64 taghi = ((u64)(u32)(t + 1)) << 32;
            const int sbase = ((bb * 2 + w) * 2 + (t & 1)) * 128 + q * 2;
            if (use_fast) {
                st_sc0(&hexf[sbase],     taghi | la);
                st_sc0(&hexf[sbase + 1], taghi | lb);
            }
            __hip_atomic_store(&hexs[sbase],     taghi | la,
                               __ATOMIC_RELAXED, __HIP_MEMORY_SCOPE_AGENT);
            __hip_atomic_store(&hexs[sbase + 1], taghi | lb,
                               __ATOMIC_RELAXED, __HIP_MEMORY_SCOPE_AGENT);
            if (t == SS - 1) {
                *(float4_t*)(&hfinal[bb * HH + w * 256 + q * 4]) =
                    float4_t{v0, v1, v2, v3};
            }
        }
        // ---- pull partner's 256 h values (tagged, parity-double-buffered)
        if (tid < 128) {
            const int pw = 1 - w;
            const int sidx = ((bb * 2 + pw) * 2 + (t & 1)) * 128 + tid;
            const u32 want = (u32)(t + 1);
            u64 v = (u64)0;
            if (use_fast) {
                int spins = FAST_SPINS;
                v = ld_sc0(&hexf[sidx]);
                while ((u32)(v >> 32) != want && --spins > 0)
                    v = ld_sc0(&hexf[sidx]);
            }
            if ((u32)(v >> 32) != want) {
                // fallback: agent-scope spin (always correct, any mapping)
                do {
                    v = __hip_atomic_load(&hexs[sidx], __ATOMIC_RELAXED,
                                          __HIP_MEMORY_SCOPE_AGENT);
                } while ((u32)(v >> 32) != want);
            }
            const int kg = pw * 256 + tid * 2;
            hbuf[(kg >> 6) * 36 + ((kg & 63) >> 1)] =
                __builtin_bit_cast(half2_t, (u32)v);
        }
        // ---- prefetch next input row
        if (tid >= 256 && tid < 320) {
            const int tn = t + 1;
            if (tn < SS) {
                const int i2 = tid - 256;
                const float2_t u = *(const float2_t*)(inputs +
                                      (size_t)(bb * SS + tn) * IN + i2 * 2);
                xh[tn & 1][(i2 >> 3) * 12 + (i2 & 7)] = h2(u[0], u[1]);
            }
        }
        __syncthreads();   // hbuf fully updated for step t+1
    }

    // ---- epilogue: output row S-1 = W_out . h_S (+ bias)
    {
        float oa = 0.f;
        const half2_t* hb = &hbuf[c * 36];
        #pragma unroll
        for (int kb = 0; kb < 8; ++kb) {
            const half8_t hv = *(const half8_t*)(hb + kb * 4);
            oa = fdot2f(wo[kb * 4 + 0], __builtin_shufflevector(hv, hv, 0, 1), oa);
            oa = fdot2f(wo[kb * 4 + 1], __builtin_shufflevector(hv, hv, 2, 3), oa);
            oa = fdot2f(wo[kb * 4 + 2], __builtin_shufflevector(hv, hv, 4, 5), oa);
            oa = fdot2f(wo[kb * 4 + 3], __builtin_shufflevector(hv, hv, 6, 7), oa);
        }
        oa += __shfl_xor(oa, 1);
        oa += __shfl_xor(oa, 2);
        oa += __shfl_xor(oa, 4);
        if (c == 0)
            outp[(size_t)(bb * SS + (SS - 1)) * OO + og] = oa + bo;
    }
}

// ---------------------------------------------------------------- launcher
extern "C" void kernel_launch(void* const* d_in, const int* in_sizes, int n_in,
                              void* d_out, int out_size, void* d_ws, size_t ws_size,
                              hipStream_t stream) {
    const float* inputs  = (const float*)d_in[0];
    const float* h0      = (const float*)d_in[1];
    const float* W_in_w  = (const float*)d_in[2];
    const float* W_in_b  = (const float*)d_in[3];
    const float* W_rec_w = (const float*)d_in[4];
    const float* W_out_w = (const float*)d_in[5];
    const float* W_out_b = (const float*)d_in[6];

    float* out    = (float*)d_out;                   // fp32 outputs
    float* hfinal = out + (size_t)BB * SS * OO;      // fp32 h_final

    const size_t slots = (size_t)BB * 2 * 2 * 128;   // u64s per region
    u64* hexf = (u64*)d_ws;
    u64* hexs = hexf + slots;
    int use_fast = 1;
    if (ws_size < 2 * slots * sizeof(u64)) {         // no room for fast region
        hexs = hexf;
        use_fast = 0;                                // pure agent-scope mode
    }

    rnn_fused<<<dim3(BB * 2), dim3(512), 0, stream>>>(
        inputs, h0, W_in_w, W_in_b, W_rec_w, W_out_w, W_out_b,
        out, hfinal, hexf, hexs, use_fast);
}

// Round 3
// 3730.326 us; speedup vs baseline: 5.8292x; 5.8292x over previous
//
#include <hip/hip_runtime.h>

// VanillaRNN B=64,S=2048,I=128,H=512,O=128. ALL inputs fp32; OUTPUT fp32
// (outputs [64][2048][128] then h_final [64][512], flat-concatenated fp32).
//
// Single fused kernel: 128 blocks x 512 threads; block pair (2b,2b+1) owns
// batch b; w=blockIdx&1 selects the H-half this WG produces. Weights live
// in VGPRs as fp16 (v_dot2_f32_f16, fp32 accumulate).
//
// SPLIT-K SCHEDULE (this round's change): each lane's 64 k-values are
// re-partitioned into 32 OWN-half k's (h values this WG produced locally
// last step -> no exchange needed) + 32 PARTNER-half k's. Per step:
//   B1: own-k MACs (rec+out rows)        ~ local data only
//   spec: speculative poll load issued   ~ latency hidden under B2
//   B2: x-projection MACs
//   D : poll partner h_t (tag t, agent scope, unbounded spin - proven
//       protocol), ds_write to hbuf partner region
//   E : raw barrier (lgkmcnt only - NO vmcnt drain)
//   F : partner-k MACs
//   reduce (8-lane butterfly), branchless 2-lane tanh split (c&1 selects
//   which 2 of the 4 j-values a lane tanh's; only c<2 lanes store),
//   G : publish own h_{t+1} (tagged u64 agent-scope stores, parity slots),
//       outp row t-1 on c==2 lanes, hbuf own-region ds_write
//   H : x_{t+1} regs->LDS (global load was issued at top of step)
//   I : raw barrier (lgkmcnt only)
// The publish->consume window is now H+I+B1+B2 (~1.1k cyc) of useful work
// instead of ~0, and the per-step vmcnt(0) drains of __syncthreads are gone.
// Exchange protocol, tags, parity double-buffering identical to the proven
// round-0 kernel: tags 1..2048 never match ws poison 0xAA..; overwrite of a
// parity slot (t vs t+2) is ordered by the partner's consumption chain.
// 128 WGs <= 256 CUs -> all co-resident, exchange cannot deadlock.
// ws usage: [B][2 wg][2 parity][128] u64 = 256 KiB.

typedef _Float16 half2_t __attribute__((ext_vector_type(2)));
typedef _Float16 half8_t __attribute__((ext_vector_type(8)));
typedef float    float2_t __attribute__((ext_vector_type(2)));
typedef float    float4_t __attribute__((ext_vector_type(4)));

#define BB 64
#define SS 2048
#define IN 128
#define HH 512
#define OO 128

using u32 = unsigned int;
using u64 = unsigned long long;

__device__ __forceinline__ float fdot2f(half2_t a, half2_t b, float c) {
#if __has_builtin(__builtin_amdgcn_fdot2)
    return __builtin_amdgcn_fdot2(a, b, c, false);
#else
    return c + (float)a[0] * (float)b[0] + (float)a[1] * (float)b[1];
#endif
}
__device__ __forceinline__ half2_t h2(float a, float b) {
    return half2_t{(_Float16)a, (_Float16)b};
}

// tanh via hw exp2 + rcp: ~6 VALU ops, no branches. |err| ~1e-7 pre-fp16.
// Clamp +-8: tanh(8)=1-2e-7 rounds to 1.0 in fp16, same as true tanh.
__device__ __forceinline__ float fast_tanh(float x) {
    x = fminf(8.0f, fmaxf(-8.0f, x));
#if __has_builtin(__builtin_amdgcn_exp2f) && __has_builtin(__builtin_amdgcn_rcpf)
    const float t = __builtin_amdgcn_exp2f(x * 2.885390081777927f); // e^{2x}
    return 1.0f - 2.0f * __builtin_amdgcn_rcpf(t + 1.0f);
#else
    return tanhf(x);
#endif
}

// Workgroup barrier that orders LDS only: waits ds ops, leaves global
// loads/stores (outp, exchange publishes, x prefetch) in flight. The
// "memory" clobber pins all memory ops on their side of the barrier.
__device__ __forceinline__ void barrier_lds() {
    asm volatile("s_waitcnt lgkmcnt(0)\n\ts_barrier" ::: "memory");
}

__global__ __launch_bounds__(512, 1) void rnn_fused(
    const float* __restrict__ inputs,   // [B][S][I]
    const float* __restrict__ h0,       // [B][H]
    const float* __restrict__ W_in,     // [H][I]
    const float* __restrict__ W_in_b,   // [H]
    const float* __restrict__ W_rec,    // [H][H]
    const float* __restrict__ W_out,    // [O][H]
    const float* __restrict__ W_out_b,  // [O]
    float* __restrict__ outp,           // fp32 [B][S][O]
    float* __restrict__ hfinal,         // fp32 [B][H]
    u64* __restrict__ hex)              // [B][2][2][128]
{
    const int tid = threadIdx.x;
    const int bb = blockIdx.x >> 1;
    const int w  = blockIdx.x & 1;     // which half of H this WG produces
    const int c  = tid & 7;            // k-lane
    const int q  = tid >> 3;           // j-quad / o index
    const int og = w * 64 + q;         // this thread-group's output column
    const int s  = c >> 2;             // sub-half within a 64-k chunk
    const int oc = w * 4 + (c & 3);    // own chunk index (0..7)
    const int pc = (1 - w) * 4 + (c & 3); // partner chunk index
    const int pw = 1 - w;

    // h as half2, chunk-strided 36 dwords. Lane c's b128 read base
    // = chunk*36 + s*16 -> banks {0,4,..,28} distinct across the 8 c-lanes
    // (broadcast across q-lanes) -> conflict-free.
    __shared__ __align__(16) half2_t hbuf[288];
    // input row as half2, chunk stride 12 dwords, double-buffered.
    __shared__ __align__(16) half2_t xh[2][96];

    // ---- persistent weights in VGPRs (fp32 -> fp16 once), split-k layout
    half2_t wro[4][16];  // W_rec[jg][own 32 k]
    half2_t wrp[4][16];  // W_rec[jg][partner 32 k]
    half2_t wi[4][8];    // W_in [jg][c*16 ..]
    half2_t woo[16];     // W_out[og][own 32 k]
    half2_t wop[16];     // W_out[og][partner 32 k]
    float bias[4];

    #pragma unroll
    for (int jj = 0; jj < 4; ++jj) {
        const int jg = w * 256 + q * 4 + jj;
        const float4_t* ro = (const float4_t*)(W_rec + jg * HH + oc * 64 + s * 32);
        const float4_t* rp = (const float4_t*)(W_rec + jg * HH + pc * 64 + s * 32);
        #pragma unroll
        for (int m = 0; m < 8; ++m) {
            const float4_t uo = ro[m];
            wro[jj][m * 2 + 0] = h2(uo[0], uo[1]);
            wro[jj][m * 2 + 1] = h2(uo[2], uo[3]);
            const float4_t up = rp[m];
            wrp[jj][m * 2 + 0] = h2(up[0], up[1]);
            wrp[jj][m * 2 + 1] = h2(up[2], up[3]);
        }
        const float4_t* irow = (const float4_t*)(W_in + jg * IN + c * 16);
        #pragma unroll
        for (int m = 0; m < 4; ++m) {
            const float4_t u = irow[m];
            wi[jj][m * 2 + 0] = h2(u[0], u[1]);
            wi[jj][m * 2 + 1] = h2(u[2], u[3]);
        }
        bias[jj] = W_in_b[jg];
    }
    {
        const float4_t* oo = (const float4_t*)(W_out + og * HH + oc * 64 + s * 32);
        const float4_t* op = (const float4_t*)(W_out + og * HH + pc * 64 + s * 32);
        #pragma unroll
        for (int m = 0; m < 8; ++m) {
            const float4_t uo = oo[m];
            woo[m * 2 + 0] = h2(uo[0], uo[1]);
            woo[m * 2 + 1] = h2(uo[2], uo[3]);
            const float4_t up = op[m];
            wop[m * 2 + 0] = h2(up[0], up[1]);
            wop[m * 2 + 1] = h2(up[2], up[3]);
        }
    }
    const float bo = W_out_b[og];

    // ---- init LDS: h = h0 (both halves, fp32->fp16), x row 0
    if (tid < 256) {
        const float2_t u = *(const float2_t*)(h0 + bb * HH + tid * 2);
        const int k = tid * 2;
        hbuf[(k >> 6) * 36 + ((k & 63) >> 1)] = h2(u[0], u[1]);
    }
    if (tid >= 256 && tid < 320) {
        const int i2 = tid - 256;
        const float2_t u = *(const float2_t*)(inputs +
                              (size_t)(bb * SS + 0) * IN + i2 * 2);
        xh[0][(i2 >> 3) * 12 + (i2 & 7)] = h2(u[0], u[1]);
    }
    __syncthreads();

    for (int t = 0; t < SS; ++t) {
        const int cur = t & 1;

        // ---- A: issue next input-row load early (wave 4), land at H
        float2_t xr;
        const bool xload = (tid >= 256 && tid < 320) && (t + 1 < SS);
        if (xload)
            xr = *(const float2_t*)(inputs +
                     (size_t)(bb * SS + (t + 1)) * IN + (tid - 256) * 2);

        // ---- B1: own-k MACs (local data, no exchange dependency)
        float acc[4] = {0.f, 0.f, 0.f, 0.f};
        float oa = 0.f;
        {
            const half2_t* hb = &hbuf[oc * 36 + s * 16];
            #pragma unroll
            for (int ob = 0; ob < 4; ++ob) {
                const half8_t hv = *(const half8_t*)(hb + ob * 4);
                const half2_t p0 = __builtin_shufflevector(hv, hv, 0, 1);
                const half2_t p1 = __builtin_shufflevector(hv, hv, 2, 3);
                const half2_t p2 = __builtin_shufflevector(hv, hv, 4, 5);
                const half2_t p3 = __builtin_shufflevector(hv, hv, 6, 7);
                #pragma unroll
                for (int jj = 0; jj < 4; ++jj) {
                    acc[jj] = fdot2f(wro[jj][ob * 4 + 0], p0, acc[jj]);
                    acc[jj] = fdot2f(wro[jj][ob * 4 + 1], p1, acc[jj]);
                    acc[jj] = fdot2f(wro[jj][ob * 4 + 2], p2, acc[jj]);
                    acc[jj] = fdot2f(wro[jj][ob * 4 + 3], p3, acc[jj]);
                }
                oa = fdot2f(woo[ob * 4 + 0], p0, oa);
                oa = fdot2f(woo[ob * 4 + 1], p1, oa);
                oa = fdot2f(woo[ob * 4 + 2], p2, oa);
                oa = fdot2f(woo[ob * 4 + 3], p3, oa);
            }
        }

        // ---- speculative poll load (latency hides under B2)
        const int sidx = ((bb * 2 + pw) * 2 + (cur ^ 1)) * 128 + tid;
        u64 spec = 0;
        if (t > 0 && tid < 128)
            spec = __hip_atomic_load(&hex[sidx], __ATOMIC_RELAXED,
                                     __HIP_MEMORY_SCOPE_AGENT);

        // ---- B2: fused input projection (lane's 16 of 128 inputs)
        {
            const half2_t* xb = &xh[cur][c * 12];
            const half8_t xv0 = *(const half8_t*)(xb);
            const half8_t xv1 = *(const half8_t*)(xb + 4);
            const half2_t x0 = __builtin_shufflevector(xv0, xv0, 0, 1);
            const half2_t x1 = __builtin_shufflevector(xv0, xv0, 2, 3);
            const half2_t x2 = __builtin_shufflevector(xv0, xv0, 4, 5);
            const half2_t x3 = __builtin_shufflevector(xv0, xv0, 6, 7);
            const half2_t x4 = __builtin_shufflevector(xv1, xv1, 0, 1);
            const half2_t x5 = __builtin_shufflevector(xv1, xv1, 2, 3);
            const half2_t x6 = __builtin_shufflevector(xv1, xv1, 4, 5);
            const half2_t x7 = __builtin_shufflevector(xv1, xv1, 6, 7);
            #pragma unroll
            for (int jj = 0; jj < 4; ++jj) {
                acc[jj] = fdot2f(wi[jj][0], x0, acc[jj]);
                acc[jj] = fdot2f(wi[jj][1], x1, acc[jj]);
                acc[jj] = fdot2f(wi[jj][2], x2, acc[jj]);
                acc[jj] = fdot2f(wi[jj][3], x3, acc[jj]);
                acc[jj] = fdot2f(wi[jj][4], x4, acc[jj]);
                acc[jj] = fdot2f(wi[jj][5], x5, acc[jj]);
                acc[jj] = fdot2f(wi[jj][6], x6, acc[jj]);
                acc[jj] = fdot2f(wi[jj][7], x7, acc[jj]);
            }
        }

        // ---- D: land partner h_t (tag t). t=0 comes from h0 init.
        if (t > 0 && tid < 128) {
            u64 v = spec;
            if ((u32)(v >> 32) != (u32)t) {
                do {
                    v = __hip_atomic_load(&hex[sidx], __ATOMIC_RELAXED,
                                          __HIP_MEMORY_SCOPE_AGENT);
                } while ((u32)(v >> 32) != (u32)t);
            }
            const int kg = pw * 256 + tid * 2;
            hbuf[(kg >> 6) * 36 + ((kg & 63) >> 1)] =
                __builtin_bit_cast(half2_t, (u32)v);
        }
        barrier_lds();   // E: partner region visible to all waves

        // ---- F: partner-k MACs
        {
            const half2_t* hb = &hbuf[pc * 36 + s * 16];
            #pragma unroll
            for (int ob = 0; ob < 4; ++ob) {
                const half8_t hv = *(const half8_t*)(hb + ob * 4);
                const half2_t p0 = __builtin_shufflevector(hv, hv, 0, 1);
                const half2_t p1 = __builtin_shufflevector(hv, hv, 2, 3);
                const half2_t p2 = __builtin_shufflevector(hv, hv, 4, 5);
                const half2_t p3 = __builtin_shufflevector(hv, hv, 6, 7);
                #pragma unroll
                for (int jj = 0; jj < 4; ++jj) {
                    acc[jj] = fdot2f(wrp[jj][ob * 4 + 0], p0, acc[jj]);
                    acc[jj] = fdot2f(wrp[jj][ob * 4 + 1], p1, acc[jj]);
                    acc[jj] = fdot2f(wrp[jj][ob * 4 + 2], p2, acc[jj]);
                    acc[jj] = fdot2f(wrp[jj][ob * 4 + 3], p3, acc[jj]);
                }
                oa = fdot2f(wop[ob * 4 + 0], p0, oa);
                oa = fdot2f(wop[ob * 4 + 1], p1, oa);
                oa = fdot2f(wop[ob * 4 + 2], p2, oa);
                oa = fdot2f(wop[ob * 4 + 3], p3, oa);
            }
        }

        // ---- butterfly reduce over the 8 c-lanes (all-reduce: every lane
        //      ends with the full sums)
        #pragma unroll
        for (int jj = 0; jj < 4; ++jj) {
            float v = acc[jj];
            v += __shfl_xor(v, 1);
            v += __shfl_xor(v, 2);
            v += __shfl_xor(v, 4);
            acc[jj] = v;
        }
        oa += __shfl_xor(oa, 1);
        oa += __shfl_xor(oa, 2);
        oa += __shfl_xor(oa, 4);

        // ---- G: branchless 2-lane tanh split + immediate publish
        {
            const bool hi = (c & 1) != 0;
            const float a0 = hi ? acc[2] : acc[0];
            const float a1 = hi ? acc[3] : acc[1];
            const float b0 = hi ? bias[2] : bias[0];
            const float b1 = hi ? bias[3] : bias[1];
            const float va = fast_tanh(a0 + b0);
            const float vb = fast_tanh(a1 + b1);
            if (c < 2) {
                const half2_t hx = h2(va, vb);
                const u64 pay = (((u64)(u32)(t + 1)) << 32) |
                                (u64)__builtin_bit_cast(u32, hx);
                const int slot = ((bb * 2 + w) * 2 + cur) * 128 + q * 2 + c;
                __hip_atomic_store(&hex[slot], pay, __ATOMIC_RELAXED,
                                   __HIP_MEMORY_SCOPE_AGENT);
                const int kg = w * 256 + q * 4 + c * 2;
                hbuf[(kg >> 6) * 36 + ((kg & 63) >> 1)] = hx;
                if (t == SS - 1)
                    *(float2_t*)(&hfinal[bb * HH + w * 256 + q * 4 + c * 2]) =
                        float2_t{va, vb};
            }
            if (c == 2 && t > 0)
                outp[(size_t)(bb * SS + (t - 1)) * OO + og] = oa + bo;
        }

        // ---- H: land next input row into LDS
        if (xload) {
            const int i2 = tid - 256;
            xh[cur ^ 1][(i2 >> 3) * 12 + (i2 & 7)] = h2(xr[0], xr[1]);
        }
        barrier_lds();   // I: hbuf own region + xh updated for step t+1
    }

    // ---- epilogue: pull partner half of h_S (tag SS, parity (SS-1)&1),
    //      then output row S-1 = W_out . h_S (+ bias)
    if (tid < 128) {
        const int sidx = ((bb * 2 + pw) * 2 + ((SS - 1) & 1)) * 128 + tid;
        u64 v;
        do {
            v = __hip_atomic_load(&hex[sidx], __ATOMIC_RELAXED,
                                  __HIP_MEMORY_SCOPE_AGENT);
        } while ((u32)(v >> 32) != (u32)SS);
        const int kg = pw * 256 + tid * 2;
        hbuf[(kg >> 6) * 36 + ((kg & 63) >> 1)] =
            __builtin_bit_cast(half2_t, (u32)v);
    }
    __syncthreads();
    {
        float oa = 0.f;
        const half2_t* ho = &hbuf[oc * 36 + s * 16];
        const half2_t* hp = &hbuf[pc * 36 + s * 16];
        #pragma unroll
        for (int ob = 0; ob < 4; ++ob) {
            const half8_t hv = *(const half8_t*)(ho + ob * 4);
            oa = fdot2f(woo[ob * 4 + 0], __builtin_shufflevector(hv, hv, 0, 1), oa);
            oa = fdot2f(woo[ob * 4 + 1], __builtin_shufflevector(hv, hv, 2, 3), oa);
            oa = fdot2f(woo[ob * 4 + 2], __builtin_shufflevector(hv, hv, 4, 5), oa);
            oa = fdot2f(woo[ob * 4 + 3], __builtin_shufflevector(hv, hv, 6, 7), oa);
        }
        #pragma unroll
        for (int ob = 0; ob < 4; ++ob) {
            const half8_t hv = *(const half8_t*)(hp + ob * 4);
            oa = fdot2f(wop[ob * 4 + 0], __builtin_shufflevector(hv, hv, 0, 1), oa);
            oa = fdot2f(wop[ob * 4 + 1], __builtin_shufflevector(hv, hv, 2, 3), oa);
            oa = fdot2f(wop[ob * 4 + 2], __builtin_shufflevector(hv, hv, 4, 5), oa);
            oa = fdot2f(wop[ob * 4 + 3], __builtin_shufflevector(hv, hv, 6, 7), oa);
        }
        oa += __shfl_xor(oa, 1);
        oa += __shfl_xor(oa, 2);
        oa += __shfl_xor(oa, 4);
        if (c == 0)
            outp[(size_t)(bb * SS + (SS - 1)) * OO + og] = oa + bo;
    }
}

// ---------------------------------------------------------------- launcher
extern "C" void kernel_launch(void* const* d_in, const int* in_sizes, int n_in,
                              void* d_out, int out_size, void* d_ws, size_t ws_size,
                              hipStream_t stream) {
    const float* inputs  = (const float*)d_in[0];
    const float* h0      = (const float*)d_in[1];
    const float* W_in_w  = (const float*)d_in[2];
    const float* W_in_b  = (const float*)d_in[3];
    const float* W_rec_w = (const float*)d_in[4];
    const float* W_out_w = (const float*)d_in[5];
    const float* W_out_b = (const float*)d_in[6];

    float* out    = (float*)d_out;                   // fp32 outputs
    float* hfinal = out + (size_t)BB * SS * OO;      // fp32 h_final
    u64* hex      = (u64*)d_ws;                      // 256 KiB exchange

    rnn_fused<<<dim3(BB * 2), dim3(512), 0, stream>>>(
        inputs, h0, W_in_w, W_in_b, W_rec_w, W_out_w, W_out_b,
        out, hfinal, hex);
}